// Round 3
// baseline (753.542 us; speedup 1.0000x reference)
//
#include <hip/hip_runtime.h>
#include <math.h>

#define T      512
#define NBATCH 512
#define IN_DIM 64
#define H      100
#define KP     208          // padded contraction rows per layer input vector
#define PBYTES 832          // KP*4: byte stride between parity buffers

// tanh(a) = 1 - 2/(exp(2a)+1)  -- overflow-safe at both ends.
__device__ __forceinline__ float fast_tanh(float a) {
    float e = __expf(2.0f * a);
    return 1.0f - 2.0f / (e + 1.0f);
}

#define DPPMOV(x, ctrl) __int_as_float(__builtin_amdgcn_update_dpp( \
        0, __float_as_int(x), (ctrl), 0xF, 0xF, true))

// weight element for concatenated row R: rows [0,kA) -> WA, [kA,kA+100) -> WB, else 0
__device__ __forceinline__ float wval(const float* __restrict__ WA,
                                      const float* __restrict__ WB,
                                      int kA, int R, int col) {
    if (R < kA) return WA[R * H + col];
    int rr = R - kA;
    return (rr < H) ? WB[rr * H + col] : 0.f;
}

__device__ __forceinline__ float4 wload4(const float* __restrict__ WA,
                                         const float* __restrict__ WB,
                                         int kA, int R0, int col) {
    return make_float4(wval(WA, WB, kA, R0 + 0, col),
                       wval(WA, WB, kA, R0 + 1, col),
                       wval(WA, WB, kA, R0 + 2, col),
                       wval(WA, WB, kA, R0 + 3, col));
}

// ---------------------------------------------------------------------------
// 512-thread block, one batch element. Unit = 16 lanes (K-split 16), 8 cols
// per unit; 13 L1 units + 13 L2 units (L2 one step behind) over waves 0-6,
// wave 7 = x-prefetch. Per thread: 104 weight floats (24 float4 rounds 0-2 +
// 8-float union reg p0..7 = L2 tail weights / L1 x-preaccumulator / wave-7 x
// pipeline). Per DOT: L1 = 2 ds_read_b128 + 64 fmaf (x-part precomputed in
// the barrier shadow from a 3-slot x ring); L2 = 3 b128 + 1 b32 + 104 fmaf.
// Reduction = R2's verified DPP pair-merge (xor1 quad_perm, xor2, xor8
// row_ror:8, xor4 = half_mirror o quad3) -- zero LDS-pipe traffic.
// Scalar fmaf only: AGPR-resident weights are read natively (R2's asm pk_fma
// forced AGPR->VGPR copies; that was the regression).
// ---------------------------------------------------------------------------

#define FMA4(r, c, v) { a##c = fmaf((v).x, w##r##_##c.x, a##c); \
                        a##c = fmaf((v).y, w##r##_##c.y, a##c); \
                        a##c = fmaf((v).z, w##r##_##c.z, a##c); \
                        a##c = fmaf((v).w, w##r##_##c.w, a##c); }
#define FROUND(r, v) FMA4(r,0,v) FMA4(r,1,v) FMA4(r,2,v) FMA4(r,3,v) \
                     FMA4(r,4,v) FMA4(r,5,v) FMA4(r,6,v) FMA4(r,7,v)

#define WDECL(c) float4 w0_##c = {0,0,0,0}, w1_##c = {0,0,0,0}, w2_##c = {0,0,0,0};
#define WLOADC(c) { w0_##c = wload4(WA, WB, kA,       4*s, cc##c); \
                    w1_##c = wload4(WA, WB, kA,  64 + 4*s, cc##c); \
                    w2_##c = wload4(WA, WB, kA, 128 + 4*s, cc##c); }
#define WCOLS(X) X(0) X(1) X(2) X(3) X(4) X(5) X(6) X(7)

// x-part precompute into p0..7 from a loaded float4 (round-0 weights)
#define SH1(c) { p##c = xv_.x * w0_##c.x; p##c = fmaf(xv_.y, w0_##c.y, p##c); \
                 p##c = fmaf(xv_.z, w0_##c.z, p##c); p##c = fmaf(xv_.w, w0_##c.w, p##c); }
#define SHCOLS() SH1(0) SH1(1) SH1(2) SH1(3) SH1(4) SH1(5) SH1(6) SH1(7)

#define SHADOW() { const float4 xv_ = *(const float4*)xptr; SHCOLS() \
    xptr += 256; if (xptr >= xend) xptr -= 768; }

#define XLOAD(wr_t, ld_t) { if ((wr_t) < T) *(float*)xptr = p0; p0 = p1;   \
    if ((ld_t) < T) p1 = xrow[(size_t)(ld_t) * IN_DIM + lane];             \
    xptr += 256; if (xptr >= xend) xptr -= 768; }

#define DOTCORE(P, hv) {                                                   \
    float a0,a1,a2,a3,a4,a5,a6,a7;                                         \
    const float4 v1_ = *(const float4*)(rb + (P) + 256);                   \
    const float4 v2_ = *(const float4*)(rb + (P) + 512);                   \
    if (isL1) { a0=p0; a1=p1; a2=p2; a3=p3; a4=p4; a5=p5; a6=p6; a7=p7; }  \
    else {                                                                 \
        const float4 v0_ = *(const float4*)(rb + (P));                     \
        const float  vt_ = *(const float*)(tb + (P));                      \
        a0 = vt_*p0; a1 = vt_*p1; a2 = vt_*p2; a3 = vt_*p3;                \
        a4 = vt_*p4; a5 = vt_*p5; a6 = vt_*p6; a7 = vt_*p7;                \
        FROUND(0, v0_)                                                     \
    }                                                                      \
    FROUND(1, v1_) FROUND(2, v2_)                                          \
    float u0_ = (q0 ? a1 : a0) + DPPMOV(q0 ? a0 : a1, 0xB1);               \
    float u1_ = (q0 ? a3 : a2) + DPPMOV(q0 ? a2 : a3, 0xB1);               \
    float u2_ = (q0 ? a5 : a4) + DPPMOV(q0 ? a4 : a5, 0xB1);               \
    float u3_ = (q0 ? a7 : a6) + DPPMOV(q0 ? a6 : a7, 0xB1);               \
    float r0_ = (q1 ? u1_ : u0_) + DPPMOV(q1 ? u0_ : u1_, 0x4E);           \
    float r1_ = (q1 ? u3_ : u2_) + DPPMOV(q1 ? u2_ : u3_, 0x4E);           \
    float z_  = (q3 ? r1_ : r0_) + DPPMOV(q3 ? r0_ : r1_, 0x128);          \
    z_ += DPPMOV(DPPMOV(z_, 0x141), 0x1B);                                 \
    hv = fast_tanh(z_ + bj); }

__global__ __launch_bounds__(512, 4)
void drnn_kernel(const float* __restrict__ x,
                 const float* __restrict__ W1x, const float* __restrict__ W1h,
                 const float* __restrict__ b1,
                 const float* __restrict__ W2x, const float* __restrict__ W2h,
                 const float* __restrict__ b2,
                 const float* __restrict__ Wo,  const float* __restrict__ bo,
                 float* __restrict__ out)
{
    // in1: [unused x-region(64) | h1(100) | pad->208]; in2: [h1(100) | h2(100) | pad]
    __shared__ __align__(16) float in1[2][KP];
    __shared__ __align__(16) float in2[2][KP];
    __shared__ __align__(16) float xring[3][IN_DIM];   // x(t) ring, written 2 bodies ahead

    const int tid  = threadIdx.x;
    const int b    = blockIdx.x;
    const int lane = tid & 63;
    const int wv   = tid >> 6;
    const int s    = lane & 15;                  // K-slice within 16-lane unit
    const int unit = wv * 4 + (lane >> 4);       // 0..31
    const bool active = (unit < 26);             // 13 L1 + 13 L2 units
    const bool isL1   = (unit < 13);
    const bool isXL   = (wv == 7);               // x-prefetch wave

    const float* __restrict__ xrow = x + (size_t)b * T * IN_DIM;

    // ---- zero-init LDS (pads stay 0; h(-1)=0; h2(-1) slot stays 0) ----
    for (int k = tid; k < 2 * KP; k += 512) {
        (&in1[0][0])[k] = 0.f;
        (&in2[0][0])[k] = 0.f;
    }

    const float* __restrict__ WA = isL1 ? W1x : W2x;
    const float* __restrict__ WB = isL1 ? W1h : W2h;
    const int kA = isL1 ? IN_DIM : H;
    const int ul = isL1 ? unit : unit - 13;
    const int j  = 8 * ((ul >= 0 && ul < 13) ? ul : 0);     // col base <= 96
    const int colof = (lane & 3) | ((lane >> 1) & 4);       // col via lane bits {0,1,3}
    const int n  = j + colof;                               // col this lane finalizes
    const int nc = (n < H) ? n : H - 1;
    const float bj = active ? (isL1 ? b1 : b2)[nc] : 0.f;
    const int cc0=(j+0<H)?j+0:H-1, cc1=(j+1<H)?j+1:H-1, cc2=(j+2<H)?j+2:H-1, cc3=(j+3<H)?j+3:H-1;
    const int cc4=(j+4<H)?j+4:H-1, cc5=(j+5<H)?j+5:H-1, cc6=(j+6<H)?j+6:H-1, cc7=(j+7<H)?j+7:H-1;

    const bool q0 = (lane & 1) != 0;
    const bool q1 = (lane & 2) != 0;
    const bool q3 = (lane & 8) != 0;

    // ---- weights: 24 float4 (rounds 0-2) + union regs p0..7 ----
    WCOLS(WDECL)
    float p0=0.f,p1=0.f,p2=0.f,p3=0.f,p4=0.f,p5=0.f,p6=0.f,p7=0.f;
    if (active) {
        WCOLS(WLOADC)
        if (!isL1) {                      // L2: tail weights (row 192+s; zero if pad)
            const int Rt = 192 + s;
            p0 = wval(WA,WB,kA,Rt,cc0); p1 = wval(WA,WB,kA,Rt,cc1);
            p2 = wval(WA,WB,kA,Rt,cc2); p3 = wval(WA,WB,kA,Rt,cc3);
            p4 = wval(WA,WB,kA,Rt,cc4); p5 = wval(WA,WB,kA,Rt,cc5);
            p6 = wval(WA,WB,kA,Rt,cc6); p7 = wval(WA,WB,kA,Rt,cc7);
        }
    }

    // ---- per-lane LDS pointers; odd parity via +PBYTES immediate ----
    const char* rb = (const char*)(isL1 ? &in1[0][0] : &in2[0][0]) + 16 * s;
    const char* tb = (const char*)&in2[0][0] + 768 + 4 * s;     // tail float 192+s

    // parity-0 store slot + write-enable
    char* st; bool dow;
    if (isL1) { st = (char*)((lane & 4) ? &in2[0][n] : &in1[0][64 + n]);
                dow = active && (n < H); }
    else      { st = (char*)&in2[0][100 + n];
                dow = active && (n < H) && !(lane & 4); }

    // x-ring rotating pointer: L1 = shadow-read slot (b+1)%3; wave7 = write slot (b+2)%3
    const int  xoff = isXL ? 4 * lane : 16 * s;
    char*       xptr = (char*)&xring[0][0] + (isXL ? 512 : 256) + xoff;
    const char* xend = (char*)&xring[0][0] + 768 + xoff;

    if (isXL) {                                   // stage x(0), x(1); pipeline x(2), x(3)
        xring[0][lane] = xrow[lane];
        xring[1][lane] = xrow[IN_DIM + lane];
        p0 = xrow[2 * IN_DIM + lane];
        p1 = xrow[3 * IN_DIM + lane];
    }

    __syncthreads();

    // L1: preaccumulate x(0)-part for body 0
    if (active && isL1) {
        const float4 xv_ = *(const float4*)((const char*)&xring[0][0] + 16 * s);
        SHCOLS()
    }

    // Body i: L1 computes h1(i); L2 computes h2(i-1). Wave 7 stages x(i+2).
    #pragma unroll 1
    for (int i = 0; i < T; i += 2) {
        // ---- even body: read parity 0, write parity 1 ----
        if (active) {
            float hv; DOTCORE(0, hv)
            if (dow && (isL1 || i > 0)) *(float*)(st + PBYTES) = hv;  // skip bogus h2(-1)
            if (isL1) SHADOW()                     // preacc x(i+1) in barrier shadow
        } else if (isXL) { XLOAD(i + 2, i + 4) }
        __syncthreads();
        // ---- odd body: read parity 1, write parity 0 ----
        if (active) {
            float hv; DOTCORE(PBYTES, hv)
            if (dow) *(float*)st = hv;
            if (isL1) SHADOW()                     // preacc x(i+2)
        } else if (isXL) { XLOAD(i + 3, i + 5) }
        __syncthreads();
    }

    // ---- tail body (parity 0): only L2, computes h2(T-1) ----
    if (active && !isL1) {
        float hv; DOTCORE(0, hv)
        if (dow) *(float*)(st + PBYTES) = hv;      // -> in2[1][100..]
    }
    __syncthreads();

    // ---- epilogue: h1(T-1) in in1[0][64..], h2(T-1) in in2[1][100..] ----
    if (tid < H)
        out[NBATCH + (size_t)b * H + tid] = in1[0][64 + tid];
    if (tid < H)
        out[NBATCH + (size_t)NBATCH * H + (size_t)b * H + tid] = in2[1][100 + tid];

    // out[b] = h2_T . Wo + bo  (wave-0 shuffle reduction)
    if (tid < 64) {
        float v = in2[1][100 + tid] * Wo[tid];
        if (tid + 64 < H) v += in2[1][100 + 64 + tid] * Wo[tid + 64];
        #pragma unroll
        for (int off = 32; off >= 1; off >>= 1) v += __shfl_down(v, off);
        if (tid == 0) out[b] = v + bo[0];
    }
}

extern "C" void kernel_launch(void* const* d_in, const int* in_sizes, int n_in,
                              void* d_out, int out_size, void* d_ws, size_t ws_size,
                              hipStream_t stream) {
    const float* x   = (const float*)d_in[0];
    const float* W1x = (const float*)d_in[1];
    const float* W1h = (const float*)d_in[2];
    const float* b1  = (const float*)d_in[3];
    const float* W2x = (const float*)d_in[4];
    const float* W2h = (const float*)d_in[5];
    const float* b2  = (const float*)d_in[6];
    const float* Wo  = (const float*)d_in[7];
    const float* bo  = (const float*)d_in[8];
    float* out = (float*)d_out;

    drnn_kernel<<<NBATCH, 512, 0, stream>>>(x, W1x, W1h, b1, W2x, W2h, b2,
                                            Wo, bo, out);
}